// Round 6
// baseline (1457.374 us; speedup 1.0000x reference)
//
#include <hip/hip_runtime.h>
#include <hip/hip_cooperative_groups.h>
#include <hip/hip_bf16.h>
#include <math.h>

namespace cg = cooperative_groups;

#define NNODES 50000
#define NEDGES 600000
#define FDIM   128
#define NCLS   40
#define H1STRIDE 136                     // LDS row stride (elems) for head
#define DEG_BLOCKS 2344
#define CVT_BLOCKS 6250
#define S1_TOTAL (DEG_BLOCKS + CVT_BLOCKS + 62)
#define NTILES ((NNODES + 63) / 64)      // 782
#define ABLOCKS ((NNODES + 3) / 4)       // 12500
#define MGRID 512                        // 2 blocks/CU guaranteed co-resident

typedef __hip_bfloat16 bf16;
typedef short bf16x8 __attribute__((ext_vector_type(8)));
typedef short bf16x4 __attribute__((ext_vector_type(4)));
typedef float f32x4  __attribute__((ext_vector_type(4)));

__device__ __forceinline__ float b2f(short u) {
    union { unsigned int i; float f; } cv;
    cv.i = ((unsigned int)(unsigned short)u) << 16;
    return cv.f;
}
__device__ __forceinline__ short f2b(float f) {
    bf16 h = __float2bfloat16(f);
    return *(const short*)&h;
}
__device__ __forceinline__ int edge_val(const int* e32, const long long* e64,
                                        int is64, int idx) {
    return is64 ? (int)e64[idx] : e32[idx];
}
__device__ __forceinline__ float ldf(const void* p, int fp32, int idx) {
    return fp32 ? ((const float*)p)[idx]
                : __bfloat162float(((const bf16*)p)[idx]);
}

struct MP {
    const int* e32; const long long* e64;
    const void* xin;
    const void *Wl1, *Wr1, *Wl2, *Wr2, *Wl3, *Wr3, *Wlin1, *Wlin2;
    const void *b1, *b2, *b3, *b4, *b5;
    int *deg, *start, *cursor, *flags, *edge_src;
    bf16x8* packed; float* biasf;
    bf16 *xb, *aggb, *bufA;
    float* out;
};

// ---------------------------------------------------------------------------
// dtype detection: b0 edge int64? (odd words zero); b1 x fp32? b2 W fp32?
__device__ __forceinline__ void detect_body(int b, int tid, const unsigned int* ei,
        const unsigned int* xp, const unsigned int* wp, int* flags, int* cnt) {
    if (tid == 0) *cnt = 0;
    __syncthreads();
    if (b == 0) {
        int nz = 0;
        for (int i = tid; i < 2048; i += 256) if (ei[2 * i + 1] != 0u) nz++;
        atomicAdd(cnt, nz);
        __syncthreads();
        if (tid == 0) flags[1] = (*cnt == 0) ? 1 : 0;
    } else {
        const unsigned int* pp = (b == 1) ? xp : wp;
        int inr = 0;
        for (int i = tid; i < 2048; i += 256) {
            unsigned int e = (pp[i] >> 7) & 0xFFu;
            if (e >= 100u && e <= 140u) inr++;
        }
        atomicAdd(cnt, inr);
        __syncthreads();
        if (tid == 0) flags[b + 1] = (*cnt < 1024) ? 1 : 0;
    }
}

// ---------------------------------------------------------------------------
// virtual-block body: deg count | x->bf16 | weight pack + bias
__device__ __forceinline__ void stage1_body(int vb, int tid, const MP& p,
                                            int is64, int xf, int wf) {
    if (vb < DEG_BLOCKS) {
        int i = vb * 256 + tid;
        if (i < NEDGES) {
            int dst = edge_val(p.e32, p.e64, is64, NEDGES + i);
            atomicAdd(&p.deg[dst], 1);
        }
        return;
    }
    if (vb < DEG_BLOCKS + CVT_BLOCKS) {
        int i = (vb - DEG_BLOCKS) * 256 + tid;
        if (i >= NNODES * FDIM / 4) return;
        if (xf) {
            float4 v = ((const float4*)p.xin)[i];
            bf16x4 o;
            o[0] = f2b(v.x); o[1] = f2b(v.y); o[2] = f2b(v.z); o[3] = f2b(v.w);
            ((bf16x4*)p.xb)[i] = o;
        } else {
            ((uint2*)p.xb)[i] = ((const uint2*)p.xin)[i];
        }
        return;
    }
    int lb = vb - DEG_BLOCKS - CVT_BLOCKS;   // 0..61
    if (lb >= 59) {
        int t = (lb - 59) * 256 + tid;
        if (t >= 5 * 128) return;
        int which = t >> 7, idx = t & 127;
        const void* srcs[5] = {p.b1, p.b2, p.b3, p.b4, p.b5};
        int n = (which == 4) ? NCLS : 128;
        float v = 0.f;
        if (idx < n) v = ldf(srcs[which], wf, idx);
        p.biasf[t] = v;
        return;
    }
    // MFMA B-fragment pack: frag(kt,nt), lane: elem j =
    //   W[kbase + (lane>>4)*8 + j][nt*16 + (lane&15)]
    // layer1 0..63 | layer2 64..127 | layer3 128..191 | lin1 192..223 |
    // lin2 224..235 (KT=4, NT=3, cols >=40 zero-padded)
    int t2 = lb * 256 + tid;
    int frag = t2 >> 6, lane = t2 & 63;
    if (frag >= 236) return;
    int q = lane >> 4, l16 = lane & 15;
    const void* W;
    int kbase, n, ldw = 128, nvalid = 128;
    if (frag < 192) {
        int g = frag >> 6, local = frag & 63;
        int kt = local >> 3, nt = local & 7;
        const void* Wl = (g == 0) ? p.Wl1 : (g == 1) ? p.Wl2 : p.Wl3;
        const void* Wr = (g == 0) ? p.Wr1 : (g == 1) ? p.Wr2 : p.Wr3;
        W = (kt < 4) ? Wl : Wr;
        kbase = (kt & 3) * 32;
        n = nt * 16 + l16;
    } else if (frag < 224) {
        int local = frag - 192;
        int kt = local >> 3, nt = local & 7;
        W = p.Wlin1; kbase = kt * 32; n = nt * 16 + l16;
    } else {
        int local = frag - 224;
        int kt = local / 3, nt = local % 3;
        W = p.Wlin2; kbase = kt * 32; n = nt * 16 + l16;
        ldw = NCLS; nvalid = NCLS;
    }
    bf16x8 v;
#pragma unroll
    for (int j = 0; j < 8; j++) {
        float e = 0.f;
        if (n < nvalid) e = ldf(W, wf, (kbase + q * 8 + j) * ldw + n);
        v[j] = f2b(e);
    }
    p.packed[frag * 64 + lane] = v;
}

// ---------------------------------------------------------------------------
__device__ __forceinline__ void alloc_body(int vb, int t, int* sA, int* sbase,
        const int* deg, int* counter, int* start, int* cursor) {
    int i = vb * 256 + t;
    int dv = (i < NNODES) ? deg[i] : 0;
    sA[t] = dv;
    __syncthreads();
    for (int off = 1; off < 256; off <<= 1) {
        int v = (t >= off) ? sA[t - off] : 0;
        __syncthreads();
        sA[t] += v;
        __syncthreads();
    }
    if (t == 255) *sbase = atomicAdd(counter, sA[255]);
    __syncthreads();
    if (i < NNODES) { int st = *sbase + sA[t] - dv; start[i] = st; cursor[i] = st; }
    __syncthreads();    // before LDS reuse
}

// ---------------------------------------------------------------------------
// Mean aggregation, wave-per-node grid-stride. 4 unpredicated clamped 16B
// gathers in flight per chunk; next node's start/deg/edge loads prefetched
// under the current gather latency. g=lane>>4 neighbor slot, c=lane&15 cols.
__device__ __forceinline__ void agg_phase(const bf16* __restrict__ x,
        const int* __restrict__ start, const int* __restrict__ deg,
        const int* __restrict__ edge_src, bf16* __restrict__ aggb,
        int gw, int nw, int lane) {
    int g = lane >> 4, c = lane & 15;
    int d = gw;
    int s = 0, dgv = 0, eidx = 0;
    if (d < NNODES) {
        s = start[d]; dgv = deg[d];
        int dc = dgv < 64 ? dgv : 64;
        eidx = (lane < dc) ? edge_src[s + lane] : 0;
    }
    while (d < NNODES) {
        int dcap = dgv < 64 ? dgv : 64;
        float acc[8];
#pragma unroll
        for (int e = 0; e < 8; e++) acc[e] = 0.f;
        for (int i = 0; i < dcap; i += 16) {
            int j0 = i + g, j1 = i + 4 + g, j2 = i + 8 + g, j3 = i + 12 + g;
            int c0 = j0 < dcap ? j0 : dcap - 1;
            int c1 = j1 < dcap ? j1 : dcap - 1;
            int c2 = j2 < dcap ? j2 : dcap - 1;
            int c3 = j3 < dcap ? j3 : dcap - 1;
            int i0 = __shfl(eidx, c0), i1 = __shfl(eidx, c1);
            int i2 = __shfl(eidx, c2), i3 = __shfl(eidx, c3);
            bf16x8 v0 = *(const bf16x8*)(x + (size_t)i0 * FDIM + c * 8);
            bf16x8 v1 = *(const bf16x8*)(x + (size_t)i1 * FDIM + c * 8);
            bf16x8 v2 = *(const bf16x8*)(x + (size_t)i2 * FDIM + c * 8);
            bf16x8 v3 = *(const bf16x8*)(x + (size_t)i3 * FDIM + c * 8);
#pragma unroll
            for (int e = 0; e < 8; e++) {
                float a0 = (j0 < dcap) ? b2f(v0[e]) : 0.f;
                float a1 = (j1 < dcap) ? b2f(v1[e]) : 0.f;
                float a2 = (j2 < dcap) ? b2f(v2[e]) : 0.f;
                float a3 = (j3 < dcap) ? b2f(v3[e]) : 0.f;
                acc[e] += (a0 + a1) + (a2 + a3);
            }
        }
        if (dgv > 64) {                  // essentially never for Poisson(12)
            for (int t2 = 64; t2 < dgv; t2++) {
                int srcn = edge_src[s + t2];
                bf16x8 v0 = *(const bf16x8*)(x + (size_t)srcn * FDIM + c * 8);
                if (g == 0) {
#pragma unroll
                    for (int e = 0; e < 8; e++) acc[e] += b2f(v0[e]);
                }
            }
        }
        // prefetch next node's metadata under the reduce/store
        int dn = d + nw;
        int sn = 0, dgn = 0, en = 0;
        if (dn < NNODES) { sn = start[dn]; dgn = deg[dn]; }
#pragma unroll
        for (int e = 0; e < 8; e++) {
            float a = acc[e];
            a += __shfl_xor(a, 16);
            a += __shfl_xor(a, 32);
            acc[e] = a;
        }
        if (g == 0) {
            float inv = (dgv > 0) ? 1.f / (float)dgv : 0.f;
            bf16x8 o;
#pragma unroll
            for (int e = 0; e < 8; e++) o[e] = f2b(acc[e] * inv);
            *(bf16x8*)(aggb + (size_t)d * FDIM + c * 8) = o;
        }
        if (dn < NNODES) {
            int dc = dgn < 64 ? dgn : 64;
            en = (lane < dc) ? edge_src[sn + lane] : 0;
        }
        d = dn; s = sn; dgv = dgn; eidx = en;
    }
}

// ---------------------------------------------------------------------------
// SAGE GEMM tile (64 rows), M-split waves (wave = 16-row slice), K=256
// (agg half | x half). Per kt: 1 row-gathered A-load (16 lines, same as
// coalesced) + 8 B-loads identical across waves (L1-hot) + 8 MFMA.
__device__ __forceinline__ void gemm_tile(int tile, int lane, int wave,
        const bf16* __restrict__ xa, const bf16* __restrict__ xb2,
        const bf16x8* __restrict__ packed, const float* __restrict__ bias,
        bf16* __restrict__ out) {
    int q = lane >> 4, l16 = lane & 15;
    int rowbase = tile * 64 + wave * 16;
    int rowA = rowbase + l16;
    if (rowA >= NNODES) rowA = NNODES - 1;
    f32x4 acc[8];
#pragma unroll
    for (int n = 0; n < 8; n++) acc[n] = (f32x4){0.f, 0.f, 0.f, 0.f};
#pragma unroll 2
    for (int kt = 0; kt < 8; kt++) {
        const bf16* src = (kt < 4) ? xa : xb2;
        int klocal = (kt & 3) * 32;
        bf16x8 a = *(const bf16x8*)(src + (size_t)rowA * FDIM + klocal + q * 8);
        bf16x8 b[8];
#pragma unroll
        for (int n = 0; n < 8; n++) b[n] = packed[(kt * 8 + n) * 64 + lane];
#pragma unroll
        for (int n = 0; n < 8; n++)
            acc[n] = __builtin_amdgcn_mfma_f32_16x16x32_bf16(a, b[n], acc[n], 0, 0, 0);
    }
#pragma unroll
    for (int n = 0; n < 8; n++) {
        int col = n * 16 + l16;
        float bv = bias[col];
#pragma unroll
        for (int r = 0; r < 4; r++) {
            int row = rowbase + q * 4 + r;
            if (row < NNODES)
                out[(size_t)row * FDIM + col] =
                    __float2bfloat16(fmaxf(acc[n][r] + bv, 0.f));
        }
    }
}

// ---------------------------------------------------------------------------
// Head tile: lin1(relu) -> LDS -> lin2(40 cols) -> log_softmax -> fp32 out
__device__ __forceinline__ void head_tile(int tile, int lane, int wave, short* h1,
        const bf16* __restrict__ h, const bf16x8* __restrict__ packed,
        const float* __restrict__ bias1, const float* __restrict__ bias2,
        float* __restrict__ out) {
    int q = lane >> 4, l16 = lane & 15;
    int rowbase = tile * 64 + wave * 16;
    int rowA = rowbase + l16;
    if (rowA >= NNODES) rowA = NNODES - 1;
    f32x4 acc[8];
#pragma unroll
    for (int n = 0; n < 8; n++) acc[n] = (f32x4){0.f, 0.f, 0.f, 0.f};
#pragma unroll 2
    for (int kt = 0; kt < 4; kt++) {
        bf16x8 a = *(const bf16x8*)(h + (size_t)rowA * FDIM + kt * 32 + q * 8);
        bf16x8 b[8];
#pragma unroll
        for (int n = 0; n < 8; n++) b[n] = packed[(192 + kt * 8 + n) * 64 + lane];
#pragma unroll
        for (int n = 0; n < 8; n++)
            acc[n] = __builtin_amdgcn_mfma_f32_16x16x32_bf16(a, b[n], acc[n], 0, 0, 0);
    }
#pragma unroll
    for (int n = 0; n < 8; n++) {
        int col = n * 16 + l16;
        float bv = bias1[col];
#pragma unroll
        for (int r = 0; r < 4; r++) {
            int rl = wave * 16 + q * 4 + r;
            h1[rl * H1STRIDE + col] = f2b(fmaxf(acc[n][r] + bv, 0.f));
        }
    }
    __syncthreads();
    f32x4 acc2[3];
#pragma unroll
    for (int n = 0; n < 3; n++) acc2[n] = (f32x4){0.f, 0.f, 0.f, 0.f};
#pragma unroll
    for (int kt = 0; kt < 4; kt++) {
        bf16x8 a = *(const bf16x8*)(h1 + (wave * 16 + l16) * H1STRIDE + kt * 32 + q * 8);
        bf16x8 b[3];
#pragma unroll
        for (int n = 0; n < 3; n++) b[n] = packed[(224 + kt * 3 + n) * 64 + lane];
#pragma unroll
        for (int n = 0; n < 3; n++)
            acc2[n] = __builtin_amdgcn_mfma_f32_16x16x32_bf16(a, b[n], acc2[n], 0, 0, 0);
    }
    const float NEG = -1e30f;
    bool v2ok = (l16 < 8);
#pragma unroll
    for (int r = 0; r < 4; r++) {
        int row = rowbase + q * 4 + r;
        float v0 = acc2[0][r] + bias2[l16];
        float v1 = acc2[1][r] + bias2[16 + l16];
        float v2 = v2ok ? (acc2[2][r] + bias2[32 + l16]) : NEG;
        float m = fmaxf(fmaxf(v0, v1), v2);
#pragma unroll
        for (int mk = 1; mk < 16; mk <<= 1) m = fmaxf(m, __shfl_xor(m, mk));
        float sden = expf(v0 - m) + expf(v1 - m) + (v2ok ? expf(v2 - m) : 0.f);
#pragma unroll
        for (int mk = 1; mk < 16; mk <<= 1) sden += __shfl_xor(sden, mk);
        float l = m + logf(sden);
        if (row < NNODES) {
            out[(size_t)row * NCLS + l16] = v0 - l;
            out[(size_t)row * NCLS + 16 + l16] = v1 - l;
            if (v2ok) out[(size_t)row * NCLS + 32 + l16] = v2 - l;
        }
    }
    __syncthreads();    // before LDS reuse next tile
}

// ---------------------------------------------------------------------------
// THE mega-kernel: whole pipeline, grid.sync between phases.
__global__ void __launch_bounds__(256, 2) k_mega(MP p) {
    __shared__ __align__(16) short h1s[64 * H1STRIDE];
    __shared__ int sb_sh;
    cg::grid_group grid = cg::this_grid();
    const int tid = threadIdx.x, bid = blockIdx.x, B = gridDim.x;
    const int lane = tid & 63, wave = tid >> 6;
    const int gw = bid * 4 + wave, nw = B * 4;

    // P0: dtype detect + zero deg + zero counter
    if (bid < 3)
        detect_body(bid, tid, (const unsigned int*)p.e32,
                    (const unsigned int*)p.xin, (const unsigned int*)p.Wl1,
                    p.flags, &sb_sh);
    if (bid == 3 && tid == 0) p.flags[0] = 0;
    for (int i = bid * 256 + tid; i < NNODES; i += B * 256) p.deg[i] = 0;
    __threadfence(); grid.sync();

    const int is64 = p.flags[1], xf = p.flags[2], wf = p.flags[3];

    // P1: deg count + x->bf16 + weight pack + bias
    for (int vb = bid; vb < S1_TOTAL; vb += B) stage1_body(vb, tid, p, is64, xf, wf);
    __threadfence(); grid.sync();

    // P2: segment allocation (scan)
    for (int vb = bid; vb < 196; vb += B)
        alloc_body(vb, tid, (int*)h1s, &sb_sh, p.deg, &p.flags[0], p.start, p.cursor);
    __threadfence(); grid.sync();

    // P3: CSR fill
    for (int i = bid * 256 + tid; i < NEDGES; i += B * 256) {
        int srcn = edge_val(p.e32, p.e64, is64, i);
        int dstn = edge_val(p.e32, p.e64, is64, NEDGES + i);
        int pos = atomicAdd(&p.cursor[dstn], 1);
        p.edge_src[pos] = srcn;
    }
    __threadfence(); grid.sync();

    bf16* bufB = p.xb;   // x dead after layer-1 gemm

    // layer 1
    agg_phase(p.xb, p.start, p.deg, p.edge_src, p.aggb, gw, nw, lane);
    __threadfence(); grid.sync();
    for (int t = bid; t < NTILES; t += B)
        gemm_tile(t, lane, wave, p.aggb, p.xb, p.packed, p.biasf, p.bufA);
    __threadfence(); grid.sync();
    // layer 2
    agg_phase(p.bufA, p.start, p.deg, p.edge_src, p.aggb, gw, nw, lane);
    __threadfence(); grid.sync();
    for (int t = bid; t < NTILES; t += B)
        gemm_tile(t, lane, wave, p.aggb, p.bufA, p.packed + 64 * 64, p.biasf + 128, bufB);
    __threadfence(); grid.sync();
    // layer 3
    agg_phase(bufB, p.start, p.deg, p.edge_src, p.aggb, gw, nw, lane);
    __threadfence(); grid.sync();
    for (int t = bid; t < NTILES; t += B)
        gemm_tile(t, lane, wave, p.aggb, bufB, p.packed + 128 * 64, p.biasf + 256, p.bufA);
    __threadfence(); grid.sync();
    // head
    for (int t = bid; t < NTILES; t += B)
        head_tile(t, lane, wave, h1s, p.bufA, p.packed, p.biasf + 384, p.biasf + 512, p.out);
}

// ---------------------------------------------------------------------------
// Fallback path (non-cooperative), same device bodies.
__global__ void k_init_f(const unsigned int* ei, const unsigned int* xp,
                         const unsigned int* wp, int* flags, int* deg) {
    __shared__ int cnt;
    int b = blockIdx.x;
    if (b < 3) detect_body(b, threadIdx.x, ei, xp, wp, flags, &cnt);
    if (b == 3 && threadIdx.x == 0) flags[0] = 0;
    if (b >= 4) {
        int i = (b - 4) * 256 + threadIdx.x;
        if (i < NNODES) deg[i] = 0;
    }
}
__global__ void k_stage1_f(MP p) {
    stage1_body(blockIdx.x, threadIdx.x, p, p.flags[1], p.flags[2], p.flags[3]);
}
__global__ void k_alloc_f(MP p) {
    __shared__ int sA[256];
    __shared__ int sb;
    alloc_body(blockIdx.x, threadIdx.x, sA, &sb, p.deg, &p.flags[0], p.start, p.cursor);
}
__global__ void k_fill_f(MP p) {
    int i = blockIdx.x * 256 + threadIdx.x;
    if (i >= NEDGES) return;
    int is64 = p.flags[1];
    int srcn = edge_val(p.e32, p.e64, is64, i);
    int dstn = edge_val(p.e32, p.e64, is64, NEDGES + i);
    int pos = atomicAdd(&p.cursor[dstn], 1);
    p.edge_src[pos] = srcn;
}
__global__ void k_agg_f(const bf16* x, const int* start, const int* deg,
                        const int* edge_src, bf16* aggb) {
    agg_phase(x, start, deg, edge_src, aggb,
              blockIdx.x * 4 + (threadIdx.x >> 6), gridDim.x * 4, threadIdx.x & 63);
}
__global__ void k_gemm_f(const bf16* xa, const bf16* xb2, const bf16x8* packed,
                         const float* bias, bf16* out) {
    gemm_tile(blockIdx.x, threadIdx.x & 63, threadIdx.x >> 6, xa, xb2, packed, bias, out);
}
__global__ void k_head_f(const bf16* h, const bf16x8* packed, const float* b1,
                         const float* b2, float* out) {
    __shared__ __align__(16) short h1[64 * H1STRIDE];
    head_tile(blockIdx.x, threadIdx.x & 63, threadIdx.x >> 6, h1, h, packed, b1, b2, out);
}

// ---------------------------------------------------------------------------
extern "C" void kernel_launch(void* const* d_in, const int* in_sizes, int n_in,
                              void* d_out, int out_size, void* d_ws, size_t ws_size,
                              hipStream_t stream) {
    char* ws = (char*)d_ws;
    size_t off = 0;
    auto take = [&](size_t bytes) {
        void* pp = ws + off;
        off = (off + bytes + 255) & ~(size_t)255;
        return pp;
    };
    MP p;
    p.e32 = (const int*)d_in[1];
    p.e64 = (const long long*)d_in[1];
    p.xin = d_in[0];
    p.Wl1 = d_in[2];  p.Wr1 = d_in[4];
    p.Wl2 = d_in[5];  p.Wr2 = d_in[7];
    p.Wl3 = d_in[8];  p.Wr3 = d_in[10];
    p.Wlin1 = d_in[11]; p.Wlin2 = d_in[13];
    p.b1 = d_in[3]; p.b2 = d_in[6]; p.b3 = d_in[9]; p.b4 = d_in[12]; p.b5 = d_in[14];
    p.deg      = (int*)take(NNODES * 4);
    p.start    = (int*)take(NNODES * 4);
    p.cursor   = (int*)take(NNODES * 4);
    p.flags    = (int*)take(256);
    p.edge_src = (int*)take(NEDGES * 4);
    p.packed   = (bf16x8*)take(236 * 64 * 16);
    p.biasf    = (float*)take(5 * 128 * 4);
    p.xb       = (bf16*)take((size_t)NNODES * FDIM * 2);
    p.aggb     = (bf16*)take((size_t)NNODES * FDIM * 2);
    p.bufA     = (bf16*)take((size_t)NNODES * FDIM * 2);
    p.out      = (float*)d_out;

    void* kargs[] = { (void*)&p };
    hipError_t err = hipLaunchCooperativeKernel((const void*)k_mega, dim3(MGRID),
                                                dim3(256), kargs, 0, stream);
    if (err != hipSuccess) {
        (void)hipGetLastError();
        bf16* bufB = p.xb;
        k_init_f<<<200, 256, 0, stream>>>((const unsigned int*)d_in[1],
                                          (const unsigned int*)d_in[0],
                                          (const unsigned int*)d_in[2],
                                          p.flags, p.deg);
        k_stage1_f<<<S1_TOTAL, 256, 0, stream>>>(p);
        k_alloc_f<<<196, 256, 0, stream>>>(p);
        k_fill_f<<<(NEDGES + 255) / 256, 256, 0, stream>>>(p);
        k_agg_f<<<ABLOCKS, 256, 0, stream>>>(p.xb, p.start, p.deg, p.edge_src, p.aggb);
        k_gemm_f<<<NTILES, 256, 0, stream>>>(p.aggb, p.xb, p.packed, p.biasf, p.bufA);
        k_agg_f<<<ABLOCKS, 256, 0, stream>>>(p.bufA, p.start, p.deg, p.edge_src, p.aggb);
        k_gemm_f<<<NTILES, 256, 0, stream>>>(p.aggb, p.bufA, p.packed + 64 * 64,
                                             p.biasf + 128, bufB);
        k_agg_f<<<ABLOCKS, 256, 0, stream>>>(bufB, p.start, p.deg, p.edge_src, p.aggb);
        k_gemm_f<<<NTILES, 256, 0, stream>>>(p.aggb, bufB, p.packed + 128 * 64,
                                             p.biasf + 256, p.bufA);
        k_head_f<<<NTILES, 256, 0, stream>>>(p.bufA, p.packed, p.biasf + 384,
                                             p.biasf + 512, p.out);
    }
}

// Round 7
// 307.316 us; speedup vs baseline: 4.7423x; 4.7423x over previous
//
#include <hip/hip_runtime.h>
#include <hip/hip_bf16.h>
#include <math.h>

#define NNODES 50000
#define NEDGES 600000
#define FDIM   128
#define NCLS   40
#define H1S    136                       // LDS row stride (elems): 2-way-free banks
#define DEG_BLOCKS 2344
#define CVT_BLOCKS 6250
#define S1_TOTAL (DEG_BLOCKS + CVT_BLOCKS + 62)
#define NTILES ((NNODES + 63) / 64)      // 782

typedef __hip_bfloat16 bf16;
typedef short bf16x8 __attribute__((ext_vector_type(8)));
typedef short bf16x4 __attribute__((ext_vector_type(4)));
typedef float f32x4  __attribute__((ext_vector_type(4)));

__device__ __forceinline__ float b2f(short u) {
    union { unsigned int i; float f; } cv;
    cv.i = ((unsigned int)(unsigned short)u) << 16;
    return cv.f;
}
__device__ __forceinline__ short f2b(float f) {
    bf16 h = __float2bfloat16(f);
    return *(const short*)&h;
}
__device__ __forceinline__ int edge_val(const int* e32, const long long* e64,
                                        int is64, int idx) {
    return is64 ? (int)e64[idx] : e32[idx];
}
__device__ __forceinline__ float ldf(const void* p, int fp32, int idx) {
    return fp32 ? ((const float*)p)[idx]
                : __bfloat162float(((const bf16*)p)[idx]);
}

struct MP {
    const int* e32; const long long* e64;
    const void* xin;
    const void *Wl1, *Wr1, *Wl2, *Wr2, *Wl3, *Wr3, *Wlin1, *Wlin2;
    const void *b1, *b2, *b3, *b4, *b5;
    int *deg, *start, *cursor, *flags, *edge_src;
    bf16x8* packed; float* biasf;
    bf16 *xb, *bufA;
    float* out;
};

// ---------------------------------------------------------------------------
// dtype detection: b0 edge int64? (odd words zero); b1 x fp32? b2 W fp32?
__device__ __forceinline__ void detect_body(int b, int tid, const unsigned int* ei,
        const unsigned int* xp, const unsigned int* wp, int* flags, int* cnt) {
    if (tid == 0) *cnt = 0;
    __syncthreads();
    if (b == 0) {
        int nz = 0;
        for (int i = tid; i < 2048; i += 256) if (ei[2 * i + 1] != 0u) nz++;
        atomicAdd(cnt, nz);
        __syncthreads();
        if (tid == 0) flags[1] = (*cnt == 0) ? 1 : 0;
    } else {
        const unsigned int* pp = (b == 1) ? xp : wp;
        int inr = 0;
        for (int i = tid; i < 2048; i += 256) {
            unsigned int e = (pp[i] >> 7) & 0xFFu;
            if (e >= 100u && e <= 140u) inr++;
        }
        atomicAdd(cnt, inr);
        __syncthreads();
        if (tid == 0) flags[b + 1] = (*cnt < 1024) ? 1 : 0;
    }
}

// ---------------------------------------------------------------------------
// virtual-block body: deg count | x->bf16 | weight pack + bias
__device__ __forceinline__ void stage1_body(int vb, int tid, const MP& p,
                                            int is64, int xf, int wf) {
    if (vb < DEG_BLOCKS) {
        int i = vb * 256 + tid;
        if (i < NEDGES) {
            int dst = edge_val(p.e32, p.e64, is64, NEDGES + i);
            atomicAdd(&p.deg[dst], 1);
        }
        return;
    }
    if (vb < DEG_BLOCKS + CVT_BLOCKS) {
        int i = (vb - DEG_BLOCKS) * 256 + tid;
        if (i >= NNODES * FDIM / 4) return;
        if (xf) {
            float4 v = ((const float4*)p.xin)[i];
            bf16x4 o;
            o[0] = f2b(v.x); o[1] = f2b(v.y); o[2] = f2b(v.z); o[3] = f2b(v.w);
            ((bf16x4*)p.xb)[i] = o;
        } else {
            ((uint2*)p.xb)[i] = ((const uint2*)p.xin)[i];
        }
        return;
    }
    int lb = vb - DEG_BLOCKS - CVT_BLOCKS;   // 0..61
    if (lb >= 59) {
        int t = (lb - 59) * 256 + tid;
        if (t >= 5 * 128) return;
        int which = t >> 7, idx = t & 127;
        const void* srcs[5] = {p.b1, p.b2, p.b3, p.b4, p.b5};
        int n = (which == 4) ? NCLS : 128;
        float v = 0.f;
        if (idx < n) v = ldf(srcs[which], wf, idx);
        p.biasf[t] = v;
        return;
    }
    // MFMA B-fragment pack: frag(kt,nt), lane: elem j =
    //   W[kbase + (lane>>4)*8 + j][nt*16 + (lane&15)]
    // layer1 0..63 | layer2 64..127 | layer3 128..191 | lin1 192..223 |
    // lin2 224..235 (KT=4, NT=3, cols >=40 zero-padded)
    int t2 = lb * 256 + tid;
    int frag = t2 >> 6, lane = t2 & 63;
    if (frag >= 236) return;
    int q = lane >> 4, l16 = lane & 15;
    const void* W;
    int kbase, n, ldw = 128, nvalid = 128;
    if (frag < 192) {
        int g = frag >> 6, local = frag & 63;
        int kt = local >> 3, nt = local & 7;
        const void* Wl = (g == 0) ? p.Wl1 : (g == 1) ? p.Wl2 : p.Wl3;
        const void* Wr = (g == 0) ? p.Wr1 : (g == 1) ? p.Wr2 : p.Wr3;
        W = (kt < 4) ? Wl : Wr;
        kbase = (kt & 3) * 32;
        n = nt * 16 + l16;
    } else if (frag < 224) {
        int local = frag - 192;
        int kt = local >> 3, nt = local & 7;
        W = p.Wlin1; kbase = kt * 32; n = nt * 16 + l16;
    } else {
        int local = frag - 224;
        int kt = local / 3, nt = local % 3;
        W = p.Wlin2; kbase = kt * 32; n = nt * 16 + l16;
        ldw = NCLS; nvalid = NCLS;
    }
    bf16x8 v;
#pragma unroll
    for (int j = 0; j < 8; j++) {
        float e = 0.f;
        if (n < nvalid) e = ldf(W, wf, (kbase + q * 8 + j) * ldw + n);
        v[j] = f2b(e);
    }
    p.packed[frag * 64 + lane] = v;
}

// ---------------------------------------------------------------------------
__global__ void k_init_f(const unsigned int* ei, const unsigned int* xp,
                         const unsigned int* wp, int* flags, int* deg) {
    __shared__ int cnt;
    int b = blockIdx.x;
    if (b < 3) detect_body(b, threadIdx.x, ei, xp, wp, flags, &cnt);
    if (b == 3 && threadIdx.x == 0) flags[0] = 0;
    if (b >= 4) {
        int i = (b - 4) * 256 + threadIdx.x;
        if (i < NNODES) deg[i] = 0;
    }
}
__global__ void k_stage1_f(MP p) {
    stage1_body(blockIdx.x, threadIdx.x, p, p.flags[1], p.flags[2], p.flags[3]);
}
__global__ void k_alloc_f(MP p) {
    __shared__ int sA[256];
    __shared__ int sb;
    int t = threadIdx.x;
    int i = blockIdx.x * 256 + t;
    int dv = (i < NNODES) ? p.deg[i] : 0;
    sA[t] = dv;
    __syncthreads();
    for (int off = 1; off < 256; off <<= 1) {
        int v = (t >= off) ? sA[t - off] : 0;
        __syncthreads();
        sA[t] += v;
        __syncthreads();
    }
    if (t == 255) sb = atomicAdd(&p.flags[0], sA[255]);
    __syncthreads();
    if (i < NNODES) {
        int st = sb + sA[t] - dv;
        p.start[i] = st;
        p.cursor[i] = st;
    }
}
__global__ void k_fill_f(MP p) {
    int i = blockIdx.x * 256 + threadIdx.x;
    if (i >= NEDGES) return;
    int is64 = p.flags[1];
    int srcn = edge_val(p.e32, p.e64, is64, i);
    int dstn = edge_val(p.e32, p.e64, is64, NEDGES + i);
    int pos = atomicAdd(&p.cursor[dstn], 1);
    p.edge_src[pos] = srcn;
}

// ---------------------------------------------------------------------------
// Phase A: wave w mean-aggregates nodes rowbase+w*16+t (t=0..15) into LDS
// rows (stride H1S). Per node: <=64 edge indices preloaded coalesced (one
// per lane), 4 clamped unpredicated 16B gathers in flight per chunk; next
// node's metadata prefetched under current gathers. g=lane>>4 neighbor
// slot, c=lane&15 col-block; cross-group reduce via shfl_xor(16/32).
// OOB nodes write zero rows (dgv=0 -> inv=0).
__device__ __forceinline__ void agg_wave_lds(const bf16* __restrict__ x,
        const int* __restrict__ start, const int* __restrict__ deg,
        const int* __restrict__ edge_src, short* __restrict__ lds,
        int rowbase, int wave, int lane) {
    const int g = lane >> 4, c = lane & 15;
    const int base = rowbase + wave * 16;
    int s = 0, dgv = 0, eidx = 0;
    if (base < NNODES) {
        s = start[base]; dgv = deg[base];
        int dc = dgv < 64 ? dgv : 64;
        eidx = (lane < dc) ? edge_src[s + lane] : 0;
    }
    for (int t = 0; t < 16; t++) {
        int nodeN = base + t + 1;
        int sn = 0, dgn = 0;
        bool haveN = (t < 15) && (nodeN < NNODES);
        if (haveN) { sn = start[nodeN]; dgn = deg[nodeN]; }
        int dcap = dgv < 64 ? dgv : 64;
        float acc[8];
#pragma unroll
        for (int e = 0; e < 8; e++) acc[e] = 0.f;
        for (int i = 0; i < dcap; i += 16) {
            int j0 = i + g, j1 = i + 4 + g, j2 = i + 8 + g, j3 = i + 12 + g;
            int c0 = j0 < dcap ? j0 : dcap - 1;
            int c1 = j1 < dcap ? j1 : dcap - 1;
            int c2 = j2 < dcap ? j2 : dcap - 1;
            int c3 = j3 < dcap ? j3 : dcap - 1;
            int i0 = __shfl(eidx, c0), i1 = __shfl(eidx, c1);
            int i2 = __shfl(eidx, c2), i3 = __shfl(eidx, c3);
            bf16x8 v0 = *(const bf16x8*)(x + (size_t)i0 * FDIM + c * 8);
            bf16x8 v1 = *(const bf16x8*)(x + (size_t)i1 * FDIM + c * 8);
            bf16x8 v2 = *(const bf16x8*)(x + (size_t)i2 * FDIM + c * 8);
            bf16x8 v3 = *(const bf16x8*)(x + (size_t)i3 * FDIM + c * 8);
#pragma unroll
            for (int e = 0; e < 8; e++) {
                float a0 = (j0 < dcap) ? b2f(v0[e]) : 0.f;
                float a1 = (j1 < dcap) ? b2f(v1[e]) : 0.f;
                float a2 = (j2 < dcap) ? b2f(v2[e]) : 0.f;
                float a3 = (j3 < dcap) ? b2f(v3[e]) : 0.f;
                acc[e] += (a0 + a1) + (a2 + a3);
            }
        }
        if (dgv > 64) {                  // essentially never for mean deg 12
            for (int t2 = 64; t2 < dgv; t2++) {
                int srcn = edge_src[s + t2];
                bf16x8 v0 = *(const bf16x8*)(x + (size_t)srcn * FDIM + c * 8);
                if (g == 0) {
#pragma unroll
                    for (int e = 0; e < 8; e++) acc[e] += b2f(v0[e]);
                }
            }
        }
        int en = 0;
        if (haveN) {
            int dc = dgn < 64 ? dgn : 64;
            en = (lane < dc) ? edge_src[sn + lane] : 0;
        }
#pragma unroll
        for (int e = 0; e < 8; e++) {
            float a = acc[e];
            a += __shfl_xor(a, 16);
            a += __shfl_xor(a, 32);
            acc[e] = a;
        }
        if (g == 0) {
            float inv = (dgv > 0) ? 1.f / (float)dgv : 0.f;
            bf16x8 o;
#pragma unroll
            for (int e = 0; e < 8; e++) o[e] = f2b(acc[e] * inv);
            *(bf16x8*)(lds + (wave * 16 + t) * H1S + c * 8) = o;
        }
        s = sn; dgv = dgn; eidx = en;
    }
}

// ---------------------------------------------------------------------------
// Phase B: SAGE GEMM, M-split waves (wave = its own 16-row slice), K=256.
// kt<4: A from LDS agg rows (this wave's own rows — no barrier needed);
// kt>=4: A root half gathered from global. B from pre-packed (L1-hot).
// TO_LDS: write relu rows back into the SAME LDS rows (all reads precede
// writes within the wave) for the fused head; else store bf16 to global.
template <bool TO_LDS>
__device__ __forceinline__ void gemm_phase(int rowbase, int lane, int wave,
        short* __restrict__ aggL, const bf16* __restrict__ xroot,
        const bf16x8* __restrict__ packed, const float* __restrict__ bias,
        bf16* __restrict__ out) {
    const int q = lane >> 4, l16 = lane & 15;
    const int rowb2 = rowbase + wave * 16;
    int rowA = rowb2 + l16;
    if (rowA >= NNODES) rowA = NNODES - 1;
    f32x4 acc[8];
#pragma unroll
    for (int n = 0; n < 8; n++) acc[n] = (f32x4){0.f, 0.f, 0.f, 0.f};
#pragma unroll 2
    for (int kt = 0; kt < 8; kt++) {
        bf16x8 a;
        if (kt < 4)
            a = *(const bf16x8*)(aggL + (wave * 16 + l16) * H1S + kt * 32 + q * 8);
        else
            a = *(const bf16x8*)(xroot + (size_t)rowA * FDIM + (kt - 4) * 32 + q * 8);
        bf16x8 b[8];
#pragma unroll
        for (int n = 0; n < 8; n++) b[n] = packed[(kt * 8 + n) * 64 + lane];
#pragma unroll
        for (int n = 0; n < 8; n++)
            acc[n] = __builtin_amdgcn_mfma_f32_16x16x32_bf16(a, b[n], acc[n], 0, 0, 0);
    }
#pragma unroll
    for (int n = 0; n < 8; n++) {
        int col = n * 16 + l16;
        float bv = bias[col];
#pragma unroll
        for (int r = 0; r < 4; r++) {
            float v = fmaxf(acc[n][r] + bv, 0.f);
            if (TO_LDS) {
                aggL[(wave * 16 + q * 4 + r) * H1S + col] = f2b(v);
            } else {
                int row = rowb2 + q * 4 + r;
                if (row < NNODES)
                    out[(size_t)row * FDIM + col] = __float2bfloat16(v);
            }
        }
    }
}

// ---------------------------------------------------------------------------
// Head: lin1 (K=128 from LDS h3, relu) -> LDS h1 -> lin2 (40 cols) ->
// log_softmax -> fp32 out. All LDS wave-local; no barriers.
__device__ __forceinline__ void head_phase(int rowbase, int lane, int wave,
        const short* __restrict__ h3, short* __restrict__ h1,
        const bf16x8* __restrict__ packed, const float* __restrict__ bias1,
        const float* __restrict__ bias2, float* __restrict__ out) {
    const int q = lane >> 4, l16 = lane & 15;
    const int rowb2 = rowbase + wave * 16;
    f32x4 acc[8];
#pragma unroll
    for (int n = 0; n < 8; n++) acc[n] = (f32x4){0.f, 0.f, 0.f, 0.f};
#pragma unroll 2
    for (int kt = 0; kt < 4; kt++) {
        bf16x8 a = *(const bf16x8*)(h3 + (wave * 16 + l16) * H1S + kt * 32 + q * 8);
        bf16x8 b[8];
#pragma unroll
        for (int n = 0; n < 8; n++) b[n] = packed[(192 + kt * 8 + n) * 64 + lane];
#pragma unroll
        for (int n = 0; n < 8; n++)
            acc[n] = __builtin_amdgcn_mfma_f32_16x16x32_bf16(a, b[n], acc[n], 0, 0, 0);
    }
#pragma unroll
    for (int n = 0; n < 8; n++) {
        int col = n * 16 + l16;
        float bv = bias1[col];
#pragma unroll
        for (int r = 0; r < 4; r++)
            h1[(wave * 16 + q * 4 + r) * H1S + col] = f2b(fmaxf(acc[n][r] + bv, 0.f));
    }
    f32x4 acc2[3];
#pragma unroll
    for (int n = 0; n < 3; n++) acc2[n] = (f32x4){0.f, 0.f, 0.f, 0.f};
#pragma unroll
    for (int kt = 0; kt < 4; kt++) {
        bf16x8 a = *(const bf16x8*)(h1 + (wave * 16 + l16) * H1S + kt * 32 + q * 8);
        bf16x8 b[3];
#pragma unroll
        for (int n = 0; n < 3; n++) b[n] = packed[(224 + kt * 3 + n) * 64 + lane];
#pragma unroll
        for (int n = 0; n < 3; n++)
            acc2[n] = __builtin_amdgcn_mfma_f32_16x16x32_bf16(a, b[n], acc2[n], 0, 0, 0);
    }
    const float NEG = -1e30f;
    bool v2ok = (l16 < 8);
#pragma unroll
    for (int r = 0; r < 4; r++) {
        int row = rowb2 + q * 4 + r;
        float v0 = acc2[0][r] + bias2[l16];
        float v1 = acc2[1][r] + bias2[16 + l16];
        float v2 = v2ok ? (acc2[2][r] + bias2[32 + l16]) : NEG;
        float m = fmaxf(fmaxf(v0, v1), v2);
#pragma unroll
        for (int mk = 1; mk < 16; mk <<= 1) m = fmaxf(m, __shfl_xor(m, mk));
        float sden = expf(v0 - m) + expf(v1 - m) + (v2ok ? expf(v2 - m) : 0.f);
#pragma unroll
        for (int mk = 1; mk < 16; mk <<= 1) sden += __shfl_xor(sden, mk);
        float l = m + logf(sden);
        if (row < NNODES) {
            out[(size_t)row * NCLS + l16] = v0 - l;
            out[(size_t)row * NCLS + 16 + l16] = v1 - l;
            if (v2ok) out[(size_t)row * NCLS + 32 + l16] = v2 - l;
        }
    }
}

// ---------------------------------------------------------------------------
// Fused layer: block = 64 nodes; agg -> LDS -> GEMM -> global bf16.
__global__ void k_layer(const bf16* __restrict__ src, const int* __restrict__ start,
                        const int* __restrict__ deg, const int* __restrict__ edge_src,
                        const bf16x8* __restrict__ packed,
                        const float* __restrict__ bias, bf16* __restrict__ out) {
    __shared__ __align__(16) short aggL[64 * H1S];
    const int lane = threadIdx.x & 63, wave = threadIdx.x >> 6;
    const int rowbase = blockIdx.x * 64;
    agg_wave_lds(src, start, deg, edge_src, aggL, rowbase, wave, lane);
    gemm_phase<false>(rowbase, lane, wave, aggL, src, packed, bias, out);
}

// Fused layer3 + head: agg -> LDS -> GEMM3 (relu rows back into same LDS as
// h3) -> lin1 -> h1 LDS -> lin2 -> log_softmax -> fp32 out. h3 never global.
__global__ void k_layer3head(const bf16* __restrict__ src,
                             const int* __restrict__ start,
                             const int* __restrict__ deg,
                             const int* __restrict__ edge_src,
                             const bf16x8* __restrict__ packed,
                             const float* __restrict__ biasf,
                             float* __restrict__ out) {
    __shared__ __align__(16) short aggL[64 * H1S];   // reused as h3
    __shared__ __align__(16) short h1[64 * H1S];
    const int lane = threadIdx.x & 63, wave = threadIdx.x >> 6;
    const int rowbase = blockIdx.x * 64;
    agg_wave_lds(src, start, deg, edge_src, aggL, rowbase, wave, lane);
    gemm_phase<true>(rowbase, lane, wave, aggL, src, packed + 128 * 64,
                     biasf + 256, nullptr);
    head_phase(rowbase, lane, wave, aggL, h1, packed, biasf + 384, biasf + 512, out);
}

// ---------------------------------------------------------------------------
extern "C" void kernel_launch(void* const* d_in, const int* in_sizes, int n_in,
                              void* d_out, int out_size, void* d_ws, size_t ws_size,
                              hipStream_t stream) {
    char* ws = (char*)d_ws;
    size_t off = 0;
    auto take = [&](size_t bytes) {
        void* pp = ws + off;
        off = (off + bytes + 255) & ~(size_t)255;
        return pp;
    };
    MP p;
    p.e32 = (const int*)d_in[1];
    p.e64 = (const long long*)d_in[1];
    p.xin = d_in[0];
    p.Wl1 = d_in[2];  p.Wr1 = d_in[4];
    p.Wl2 = d_in[5];  p.Wr2 = d_in[7];
    p.Wl3 = d_in[8];  p.Wr3 = d_in[10];
    p.Wlin1 = d_in[11]; p.Wlin2 = d_in[13];
    p.b1 = d_in[3]; p.b2 = d_in[6]; p.b3 = d_in[9]; p.b4 = d_in[12]; p.b5 = d_in[14];
    p.deg      = (int*)take(NNODES * 4);
    p.start    = (int*)take(NNODES * 4);
    p.cursor   = (int*)take(NNODES * 4);
    p.flags    = (int*)take(256);
    p.edge_src = (int*)take(NEDGES * 4);
    p.packed   = (bf16x8*)take(236 * 64 * 16);
    p.biasf    = (float*)take(5 * 128 * 4);
    p.xb       = (bf16*)take((size_t)NNODES * FDIM * 2);
    p.bufA     = (bf16*)take((size_t)NNODES * FDIM * 2);
    p.out      = (float*)d_out;
    bf16* bufB = p.xb;    // x dead after layer 1

    k_init_f<<<200, 256, 0, stream>>>((const unsigned int*)d_in[1],
                                      (const unsigned int*)d_in[0],
                                      (const unsigned int*)d_in[2],
                                      p.flags, p.deg);
    k_stage1_f<<<S1_TOTAL, 256, 0, stream>>>(p);
    k_alloc_f<<<(NNODES + 255) / 256, 256, 0, stream>>>(p);
    k_fill_f<<<(NEDGES + 255) / 256, 256, 0, stream>>>(p);

    // layer 1: xb -> bufA
    k_layer<<<NTILES, 256, 0, stream>>>(p.xb, p.start, p.deg, p.edge_src,
                                        p.packed, p.biasf, p.bufA);
    // layer 2: bufA -> bufB (aliases xb)
    k_layer<<<NTILES, 256, 0, stream>>>(p.bufA, p.start, p.deg, p.edge_src,
                                        p.packed + 64 * 64, p.biasf + 128, bufB);
    // layer 3 + head: bufB -> out
    k_layer3head<<<NTILES, 256, 0, stream>>>(bufB, p.start, p.deg, p.edge_src,
                                             p.packed, p.biasf, p.out);
}

// Round 8
// 283.546 us; speedup vs baseline: 5.1398x; 1.0838x over previous
//
#include <hip/hip_runtime.h>
#include <hip/hip_bf16.h>
#include <math.h>

#define NNODES 50000
#define NEDGES 600000
#define FDIM   128
#define NCLS   40
#define DEG_BLOCKS 2344
#define CVT_BLOCKS 6251                  // covers (NNODES+1) rows (zero sentinel row)
#define S1_TOTAL (DEG_BLOCKS + CVT_BLOCKS + 62)
#define NT32 ((NNODES + 31) / 32)        // 1563 tiles of 32 rows
#define ESRC_CAP 1360128                 // padded CSR capacity (+ slack)

typedef __hip_bfloat16 bf16;
typedef short bf16x8 __attribute__((ext_vector_type(8)));
typedef short bf16x4 __attribute__((ext_vector_type(4)));
typedef float f32x4  __attribute__((ext_vector_type(4)));

__device__ __forceinline__ float b2f(short u) {
    union { unsigned int i; float f; } cv;
    cv.i = ((unsigned int)(unsigned short)u) << 16;
    return cv.f;
}
__device__ __forceinline__ short f2b(float f) {
    bf16 h = __float2bfloat16(f);
    return *(const short*)&h;
}
__device__ __forceinline__ int edge_val(const int* e32, const long long* e64,
                                        int is64, int idx) {
    return is64 ? (int)e64[idx] : e32[idx];
}
__device__ __forceinline__ float ldf(const void* p, int fp32, int idx) {
    return fp32 ? ((const float*)p)[idx]
                : __bfloat162float(((const bf16*)p)[idx]);
}
// LDS addressing: flat 128-short rows, 8-short chunks XOR-swizzled by row&15.
// Writers (16B chunks) and MFMA A-readers both resolve to 2-way (free) banks.
__device__ __forceinline__ int lidx(int row, int col) {
    return row * 128 + ((((col >> 3) ^ (row & 15)) << 3) | (col & 7));
}

struct MP {
    const int* e32; const long long* e64;
    const void* xin;
    const void *Wl1, *Wr1, *Wl2, *Wr2, *Wl3, *Wr3, *Wlin1, *Wlin2;
    const void *b1, *b2, *b3, *b4, *b5;
    int *deg, *start, *cursor, *flags, *edge_src;
    bf16x8* packed; float* biasf;
    bf16 *xb, *bufA;
    float* out;
};

// ---------------------------------------------------------------------------
// dtype detection: b0 edge int64? (odd words zero); b1 x fp32? b2 W fp32?
__device__ __forceinline__ void detect_body(int b, int tid, const unsigned int* ei,
        const unsigned int* xp, const unsigned int* wp, int* flags, int* cnt) {
    if (tid == 0) *cnt = 0;
    __syncthreads();
    if (b == 0) {
        int nz = 0;
        for (int i = tid; i < 2048; i += 256) if (ei[2 * i + 1] != 0u) nz++;
        atomicAdd(cnt, nz);
        __syncthreads();
        if (tid == 0) flags[1] = (*cnt == 0) ? 1 : 0;
    } else {
        const unsigned int* pp = (b == 1) ? xp : wp;
        int inr = 0;
        for (int i = tid; i < 2048; i += 256) {
            unsigned int e = (pp[i] >> 7) & 0xFFu;
            if (e >= 100u && e <= 140u) inr++;
        }
        atomicAdd(cnt, inr);
        __syncthreads();
        if (tid == 0) flags[b + 1] = (*cnt < 1024) ? 1 : 0;
    }
}

// k_init: dtype detect + zero deg + sentinel-fill edge_src + zero counter
__global__ void k_init_f(const unsigned int* ei, const unsigned int* xp,
                         const unsigned int* wp, int* flags, int* deg,
                         int* edge_src) {
    __shared__ int cnt;
    int b = blockIdx.x, tid = threadIdx.x, B = gridDim.x;
    if (b < 3) detect_body(b, tid, ei, xp, wp, flags, &cnt);
    if (b == 3 && tid == 0) flags[0] = 0;
    for (int i = b * 256 + tid; i < NNODES; i += B * 256) deg[i] = 0;
    for (int i = b * 256 + tid; i < ESRC_CAP; i += B * 256) edge_src[i] = NNODES;
}

// ---------------------------------------------------------------------------
// stage1: deg count | x->bf16 (+ zero row NNODES) | weight pack + bias
__device__ __forceinline__ void stage1_body(int vb, int tid, const MP& p,
                                            int is64, int xf, int wf) {
    if (vb < DEG_BLOCKS) {
        int i = vb * 256 + tid;
        if (i < NEDGES) {
            int dst = edge_val(p.e32, p.e64, is64, NEDGES + i);
            atomicAdd(&p.deg[dst], 1);
        }
        return;
    }
    if (vb < DEG_BLOCKS + CVT_BLOCKS) {
        int i = (vb - DEG_BLOCKS) * 256 + tid;
        if (i >= (NNODES + 1) * FDIM / 4) return;
        if (i >= NNODES * FDIM / 4) {            // sentinel zero row
            bf16x4 z = (bf16x4){0, 0, 0, 0};
            ((bf16x4*)p.xb)[i] = z;
        } else if (xf) {
            float4 v = ((const float4*)p.xin)[i];
            bf16x4 o;
            o[0] = f2b(v.x); o[1] = f2b(v.y); o[2] = f2b(v.z); o[3] = f2b(v.w);
            ((bf16x4*)p.xb)[i] = o;
        } else {
            ((uint2*)p.xb)[i] = ((const uint2*)p.xin)[i];
        }
        return;
    }
    int lb = vb - DEG_BLOCKS - CVT_BLOCKS;   // 0..61
    if (lb >= 59) {
        int t = (lb - 59) * 256 + tid;
        if (t >= 5 * 128) return;
        int which = t >> 7, idx = t & 127;
        const void* srcs[5] = {p.b1, p.b2, p.b3, p.b4, p.b5};
        int n = (which == 4) ? NCLS : 128;
        float v = 0.f;
        if (idx < n) v = ldf(srcs[which], wf, idx);
        p.biasf[t] = v;
        return;
    }
    // MFMA B-fragment pack: frag(kt,nt), lane: elem j =
    //   W[kbase + (lane>>4)*8 + j][nt*16 + (lane&15)]
    // layer1 0..63 | layer2 64..127 | layer3 128..191 | lin1 192..223 |
    // lin2 224..235 (KT=4, NT=3, cols >=40 zero-padded)
    int t2 = lb * 256 + tid;
    int frag = t2 >> 6, lane = t2 & 63;
    if (frag >= 236) return;
    int q = lane >> 4, l16 = lane & 15;
    const void* W;
    int kbase, n, ldw = 128, nvalid = 128;
    if (frag < 192) {
        int g = frag >> 6, local = frag & 63;
        int kt = local >> 3, nt = local & 7;
        const void* Wl = (g == 0) ? p.Wl1 : (g == 1) ? p.Wl2 : p.Wl3;
        const void* Wr = (g == 0) ? p.Wr1 : (g == 1) ? p.Wr2 : p.Wr3;
        W = (kt < 4) ? Wl : Wr;
        kbase = (kt & 3) * 32;
        n = nt * 16 + l16;
    } else if (frag < 224) {
        int local = frag - 192;
        int kt = local >> 3, nt = local & 7;
        W = p.Wlin1; kbase = kt * 32; n = nt * 16 + l16;
    } else {
        int local = frag - 224;
        int kt = local / 3, nt = local % 3;
        W = p.Wlin2; kbase = kt * 32; n = nt * 16 + l16;
        ldw = NCLS; nvalid = NCLS;
    }
    bf16x8 v;
#pragma unroll
    for (int j = 0; j < 8; j++) {
        float e = 0.f;
        if (n < nvalid) e = ldf(W, wf, (kbase + q * 8 + j) * ldw + n);
        v[j] = f2b(e);
    }
    p.packed[frag * 64 + lane] = v;
}
__global__ void k_stage1_f(MP p) {
    stage1_body(blockIdx.x, threadIdx.x, p, p.flags[1], p.flags[2], p.flags[3]);
}

// alloc: segments rounded up to x16 (padding slots hold sentinel NNODES)
__global__ void k_alloc_f(MP p) {
    __shared__ int sA[256];
    __shared__ int sb;
    int t = threadIdx.x;
    int i = blockIdx.x * 256 + t;
    int dv = (i < NNODES) ? p.deg[i] : 0;
    int pv = (dv + 15) & ~15;
    sA[t] = pv;
    __syncthreads();
    for (int off = 1; off < 256; off <<= 1) {
        int v = (t >= off) ? sA[t - off] : 0;
        __syncthreads();
        sA[t] += v;
        __syncthreads();
    }
    if (t == 255) sb = atomicAdd(&p.flags[0], sA[255]);
    __syncthreads();
    if (i < NNODES) {
        int st = sb + sA[t] - pv;
        p.start[i] = st;
        p.cursor[i] = st;
    }
}
__global__ void k_fill_f(MP p) {
    int i = blockIdx.x * 256 + threadIdx.x;
    if (i >= NEDGES) return;
    int is64 = p.flags[1];
    int srcn = edge_val(p.e32, p.e64, is64, i);
    int dstn = edge_val(p.e32, p.e64, is64, NEDGES + i);
    int pos = atomicAdd(&p.cursor[dstn], 1);
    p.edge_src[pos] = srcn;
}

// ---------------------------------------------------------------------------
// Agg: wave w aggregates 8 nodes (rowbase + w*8 + t) into LDS rows.
// Padded CSR: dcap multiple of 16; 4 unconditional 16B gathers in flight;
// sentinel rows are zero. Next node's metadata prefetched under gathers.
__device__ __forceinline__ void agg_wave(const bf16* __restrict__ x,
        const int* __restrict__ start, const int* __restrict__ deg,
        const int* __restrict__ edge_src, short* __restrict__ lds,
        int rowbase, int wave, int lane) {
    const int g = lane >> 4, c = lane & 15;
    const int base = rowbase + wave * 8;
    int s = 0, dgv = 0, eidx = NNODES;
    if (base < NNODES) {
        s = start[base]; dgv = deg[base];
        eidx = edge_src[s + lane];
    }
    for (int t = 0; t < 8; t++) {
        int nodeN = base + t + 1;
        int sn = 0, dgn = 0;
        bool haveN = (t < 7) && (nodeN < NNODES);
        if (haveN) { sn = start[nodeN]; dgn = deg[nodeN]; }
        int dcap = dgv < 64 ? ((dgv + 15) & ~15) : 64;
        float acc[8];
#pragma unroll
        for (int e = 0; e < 8; e++) acc[e] = 0.f;
        for (int i = 0; i < dcap; i += 16) {
            int i0 = __shfl(eidx, i + g);
            int i1 = __shfl(eidx, i + 4 + g);
            int i2 = __shfl(eidx, i + 8 + g);
            int i3 = __shfl(eidx, i + 12 + g);
            bf16x8 v0 = *(const bf16x8*)(x + (size_t)i0 * FDIM + c * 8);
            bf16x8 v1 = *(const bf16x8*)(x + (size_t)i1 * FDIM + c * 8);
            bf16x8 v2 = *(const bf16x8*)(x + (size_t)i2 * FDIM + c * 8);
            bf16x8 v3 = *(const bf16x8*)(x + (size_t)i3 * FDIM + c * 8);
#pragma unroll
            for (int e = 0; e < 8; e++)
                acc[e] += (b2f(v0[e]) + b2f(v1[e])) + (b2f(v2[e]) + b2f(v3[e]));
        }
        if (dgv > 64) {                  // essentially never for mean deg 12
            for (int t2 = 64; t2 < dgv; t2++) {
                int srcn = edge_src[s + t2];
                bf16x8 v0 = *(const bf16x8*)(x + (size_t)srcn * FDIM + c * 8);
                if (g == 0) {
#pragma unroll
                    for (int e = 0; e < 8; e++) acc[e] += b2f(v0[e]);
                }
            }
        }
        int en = NNODES;
        if (haveN) en = edge_src[sn + lane];
#pragma unroll
        for (int e = 0; e < 8; e++) {
            float a = acc[e];
            a += __shfl_xor(a, 16);
            a += __shfl_xor(a, 32);
            acc[e] = a;
        }
        if (g == 0) {
            float inv = (dgv > 0) ? 1.f / (float)dgv : 0.f;
            bf16x8 o;
#pragma unroll
            for (int e = 0; e < 8; e++) o[e] = f2b(acc[e] * inv);
            *(bf16x8*)(lds + lidx(wave * 8 + t, c * 8)) = o;
        }
        s = sn; dgv = dgn; eidx = en;
    }
}

// ---------------------------------------------------------------------------
// GEMM over 32-row tile, 8 virtual tiles: wave -> mt = w&1 (16 rows),
// half = w>>1 (64 cols = 4 nt). K=256: kt<4 agg (LDS), kt>=4 root (global).
// TO_LDS: relu rows written back into the same LDS buffer (h3 for head).
// Sentinel row NNODES written zero in global outputs.
template <bool TO_LDS>
__device__ __forceinline__ void gemm_phase(int rowbase, int lane, int wave,
        short* __restrict__ aggL, const bf16* __restrict__ xroot,
        const bf16x8* __restrict__ packed, const float* __restrict__ bias,
        bf16* __restrict__ out) {
    const int q = lane >> 4, l16 = lane & 15;
    const int mt = wave & 1, half = wave >> 1;
    const int rowb2 = rowbase + mt * 16;
    int rowA = rowb2 + l16;
    if (rowA >= NNODES) rowA = NNODES - 1;
    f32x4 acc[4];
#pragma unroll
    for (int n = 0; n < 4; n++) acc[n] = (f32x4){0.f, 0.f, 0.f, 0.f};
#pragma unroll 2
    for (int kt = 0; kt < 8; kt++) {
        bf16x8 a;
        if (kt < 4)
            a = *(const bf16x8*)(aggL + lidx(mt * 16 + l16, kt * 32 + q * 8));
        else
            a = *(const bf16x8*)(xroot + (size_t)rowA * FDIM + (kt - 4) * 32 + q * 8);
        bf16x8 b[4];
#pragma unroll
        for (int n = 0; n < 4; n++)
            b[n] = packed[(kt * 8 + half * 4 + n) * 64 + lane];
#pragma unroll
        for (int n = 0; n < 4; n++)
            acc[n] = __builtin_amdgcn_mfma_f32_16x16x32_bf16(a, b[n], acc[n], 0, 0, 0);
    }
#pragma unroll
    for (int n = 0; n < 4; n++) {
        int col = (half * 4 + n) * 16 + l16;
        float bv = bias[col];
#pragma unroll
        for (int r = 0; r < 4; r++) {
            float v = fmaxf(acc[n][r] + bv, 0.f);
            if (TO_LDS) {
                aggL[lidx(mt * 16 + q * 4 + r, col)] = f2b(v);
            } else {
                int row = rowb2 + q * 4 + r;
                if (row < NNODES)
                    out[(size_t)row * FDIM + col] = __float2bfloat16(v);
                else if (row == NNODES)
                    out[(size_t)row * FDIM + col] = __float2bfloat16(0.f);
            }
        }
    }
}

// ---------------------------------------------------------------------------
// Head: lin1 (K=128 from h3 LDS, relu, 8-wave split) -> h1 LDS -> barrier ->
// lin2 (40 cols, waves 0..1) -> log_softmax -> fp32 out.
__device__ __forceinline__ void head_phase(int rowbase, int lane, int wave,
        const short* __restrict__ h3, short* __restrict__ h1,
        const bf16x8* __restrict__ packed, const float* __restrict__ bias1,
        const float* __restrict__ bias2, float* __restrict__ out) {
    const int q = lane >> 4, l16 = lane & 15;
    const int mt = wave & 1, half = wave >> 1;
    f32x4 acc[4];
#pragma unroll
    for (int n = 0; n < 4; n++) acc[n] = (f32x4){0.f, 0.f, 0.f, 0.f};
#pragma unroll 2
    for (int kt = 0; kt < 4; kt++) {
        bf16x8 a = *(const bf16x8*)(h3 + lidx(mt * 16 + l16, kt * 32 + q * 8));
        bf16x8 b[4];
#pragma unroll
        for (int n = 0; n < 4; n++)
            b[n] = packed[(192 + kt * 8 + half * 4 + n) * 64 + lane];
#pragma unroll
        for (int n = 0; n < 4; n++)
            acc[n] = __builtin_amdgcn_mfma_f32_16x16x32_bf16(a, b[n], acc[n], 0, 0, 0);
    }
#pragma unroll
    for (int n = 0; n < 4; n++) {
        int col = (half * 4 + n) * 16 + l16;
        float bv = bias1[col];
#pragma unroll
        for (int r = 0; r < 4; r++)
            h1[lidx(mt * 16 + q * 4 + r, col)] = f2b(fmaxf(acc[n][r] + bv, 0.f));
    }
    __syncthreads();
    if (wave >= 2) return;
    f32x4 acc2[3];
#pragma unroll
    for (int n = 0; n < 3; n++) acc2[n] = (f32x4){0.f, 0.f, 0.f, 0.f};
#pragma unroll
    for (int kt = 0; kt < 4; kt++) {
        bf16x8 a = *(const bf16x8*)(h1 + lidx(wave * 16 + l16, kt * 32 + q * 8));
        bf16x8 b[3];
#pragma unroll
        for (int n = 0; n < 3; n++) b[n] = packed[(224 + kt * 3 + n) * 64 + lane];
#pragma unroll
        for (int n = 0; n < 3; n++)
            acc2[n] = __builtin_amdgcn_mfma_f32_16x16x32_bf16(a, b[n], acc2[n], 0, 0, 0);
    }
    const float NEG = -1e30f;
    bool v2ok = (l16 < 8);
#pragma unroll
    for (int r = 0; r < 4; r++) {
        int row = rowbase + wave * 16 + q * 4 + r;
        float v0 = acc2[0][r] + bias2[l16];
        float v1 = acc2[1][r] + bias2[16 + l16];
        float v2 = v2ok ? (acc2[2][r] + bias2[32 + l16]) : NEG;
        float m = fmaxf(fmaxf(v0, v1), v2);
#pragma unroll
        for (int mk = 1; mk < 16; mk <<= 1) m = fmaxf(m, __shfl_xor(m, mk));
        float sden = expf(v0 - m) + expf(v1 - m) + (v2ok ? expf(v2 - m) : 0.f);
#pragma unroll
        for (int mk = 1; mk < 16; mk <<= 1) sden += __shfl_xor(sden, mk);
        float l = m + logf(sden);
        if (row < NNODES) {
            out[(size_t)row * NCLS + l16] = v0 - l;
            out[(size_t)row * NCLS + 16 + l16] = v1 - l;
            if (v2ok) out[(size_t)row * NCLS + 32 + l16] = v2 - l;
        }
    }
}

// ---------------------------------------------------------------------------
__global__ void k_layer(const bf16* __restrict__ src, const int* __restrict__ start,
                        const int* __restrict__ deg, const int* __restrict__ edge_src,
                        const bf16x8* __restrict__ packed,
                        const float* __restrict__ bias, bf16* __restrict__ out) {
    __shared__ __align__(16) short aggL[32 * 128];
    const int lane = threadIdx.x & 63, wave = threadIdx.x >> 6;
    const int rowbase = blockIdx.x * 32;
    agg_wave(src, start, deg, edge_src, aggL, rowbase, wave, lane);
    __syncthreads();
    gemm_phase<false>(rowbase, lane, wave, aggL, src, packed, bias, out);
}

__global__ void k_layer3head(const bf16* __restrict__ src,
                             const int* __restrict__ start,
                             const int* __restrict__ deg,
                             const int* __restrict__ edge_src,
                             const bf16x8* __restrict__ packed,
                             const float* __restrict__ biasf,
                             float* __restrict__ out) {
    __shared__ __align__(16) short aggL[32 * 128];   // reused as h3
    __shared__ __align__(16) short h1[32 * 128];
    const int lane = threadIdx.x & 63, wave = threadIdx.x >> 6;
    const int rowbase = blockIdx.x * 32;
    agg_wave(src, start, deg, edge_src, aggL, rowbase, wave, lane);
    __syncthreads();
    gemm_phase<true>(rowbase, lane, wave, aggL, src, packed + 128 * 64,
                     biasf + 256, nullptr);
    __syncthreads();
    head_phase(rowbase, lane, wave, aggL, h1, packed, biasf + 384, biasf + 512, out);
}

// ---------------------------------------------------------------------------
extern "C" void kernel_launch(void* const* d_in, const int* in_sizes, int n_in,
                              void* d_out, int out_size, void* d_ws, size_t ws_size,
                              hipStream_t stream) {
    char* ws = (char*)d_ws;
    size_t off = 0;
    auto take = [&](size_t bytes) {
        void* pp = ws + off;
        off = (off + bytes + 255) & ~(size_t)255;
        return pp;
    };
    MP p;
    p.e32 = (const int*)d_in[1];
    p.e64 = (const long long*)d_in[1];
    p.xin = d_in[0];
    p.Wl1 = d_in[2];  p.Wr1 = d_in[4];
    p.Wl2 = d_in[5];  p.Wr2 = d_in[7];
    p.Wl3 = d_in[8];  p.Wr3 = d_in[10];
    p.Wlin1 = d_in[11]; p.Wlin2 = d_in[13];
    p.b1 = d_in[3]; p.b2 = d_in[6]; p.b3 = d_in[9]; p.b4 = d_in[12]; p.b5 = d_in[14];
    p.deg      = (int*)take(NNODES * 4);
    p.start    = (int*)take(NNODES * 4);
    p.cursor   = (int*)take(NNODES * 4);
    p.flags    = (int*)take(256);
    p.edge_src = (int*)take((ESRC_CAP + 256) * 4);
    p.packed   = (bf16x8*)take(236 * 64 * 16);
    p.biasf    = (float*)take(5 * 128 * 4);
    p.xb       = (bf16*)take((size_t)(NNODES + 1) * FDIM * 2);
    p.bufA     = (bf16*)take((size_t)(NNODES + 1) * FDIM * 2);
    p.out      = (float*)d_out;
    bf16* bufB = p.xb;    // x dead after layer 1

    k_init_f<<<512, 256, 0, stream>>>((const unsigned int*)d_in[1],
                                      (const unsigned int*)d_in[0],
                                      (const unsigned int*)d_in[2],
                                      p.flags, p.deg, p.edge_src);
    k_stage1_f<<<S1_TOTAL, 256, 0, stream>>>(p);
    k_alloc_f<<<(NNODES + 255) / 256, 256, 0, stream>>>(p);
    k_fill_f<<<(NEDGES + 255) / 256, 256, 0, stream>>>(p);

    // layer 1: xb -> bufA
    k_layer<<<NT32, 256, 0, stream>>>(p.xb, p.start, p.deg, p.edge_src,
                                      p.packed, p.biasf, p.bufA);
    // layer 2: bufA -> bufB (aliases xb)
    k_layer<<<NT32, 256, 0, stream>>>(p.bufA, p.start, p.deg, p.edge_src,
                                      p.packed + 64 * 64, p.biasf + 128, bufB);
    // layer 3 + head: bufB -> out
    k_layer3head<<<NT32, 256, 0, stream>>>(bufB, p.start, p.deg, p.edge_src,
                                           p.packed, p.biasf, p.out);
}